// Round 1
// baseline (510.289 us; speedup 1.0000x reference)
//
#include <hip/hip_runtime.h>

#define BB 2
#define SDIM 1024
#define DDIM 128
#define TILE 64
#define K1_ROWS 8

#define F4GET(v,k) ((k)==0?(v).x:((k)==1?(v).y:((k)==2?(v).z:(v).w)))

// Swizzled LDS float4 pointer: column-XOR on float4 granularity breaks the
// power-of-2 row stride so ds_read_b128 of 4/16 distinct rows at the same
// d-chunk spreads across bank groups (hi reads conflict-free, hjb 2-way=free).
__device__ __forceinline__ float4* lds_ptr4(float* base, int row, int c4) {
    int swz = c4 ^ ((row >> 1) & 7);
    return reinterpret_cast<float4*>(base + row * DDIM + swz * 4);
}

// ---------------- Kernel 1: projections + row dot products ----------------
// hi[n][d]  = sum_k x[n][k] * W1[k][d]
// hjb[n][d] = sum_k x[n][k] * W1[D+k][d] + b1[d]
// si2[n] = 0.5 * (hi[n] . w2)
// sj2[n] = 0.5 * (hjb[n] . w2) + b2
__global__ __launch_bounds__(128) void proj_kernel(
    const float* __restrict__ x, const float* __restrict__ W1,
    const float* __restrict__ b1, const float* __restrict__ W2,
    const float* __restrict__ b2,
    float* __restrict__ hi, float* __restrict__ hjb,
    float* __restrict__ si2, float* __restrict__ sj2)
{
    __shared__ float sX[K1_ROWS][DDIM];
    __shared__ float sRed[2][2 * K1_ROWS];
    const int d = threadIdx.x;
    const int r0 = blockIdx.x * K1_ROWS;

    const float4* xsrc = reinterpret_cast<const float4*>(x + (size_t)r0 * DDIM);
    float4* xdst = reinterpret_cast<float4*>(&sX[0][0]);
    #pragma unroll
    for (int p = 0; p < (K1_ROWS * DDIM / 4) / 128; ++p)
        xdst[p * 128 + d] = xsrc[p * 128 + d];
    __syncthreads();

    float acc_a[K1_ROWS], acc_b[K1_ROWS];
    #pragma unroll
    for (int r = 0; r < K1_ROWS; ++r) { acc_a[r] = 0.f; acc_b[r] = 0.f; }

    for (int k = 0; k < DDIM; k += 4) {
        float4 xv[K1_ROWS];
        #pragma unroll
        for (int r = 0; r < K1_ROWS; ++r)
            xv[r] = *reinterpret_cast<const float4*>(&sX[r][k]);
        #pragma unroll
        for (int kk = 0; kk < 4; ++kk) {
            float wa = W1[(k + kk) * DDIM + d];
            float wb = W1[(DDIM + k + kk) * DDIM + d];
            #pragma unroll
            for (int r = 0; r < K1_ROWS; ++r) {
                float xr = F4GET(xv[r], kk);
                acc_a[r] = fmaf(xr, wa, acc_a[r]);
                acc_b[r] = fmaf(xr, wb, acc_b[r]);
            }
        }
    }

    const float bv  = b1[d];
    const float wv  = W2[d];
    const float b2v = b2[0];
    #pragma unroll
    for (int r = 0; r < K1_ROWS; ++r) acc_b[r] += bv;

    #pragma unroll
    for (int r = 0; r < K1_ROWS; ++r) {
        hi [(size_t)(r0 + r) * DDIM + d] = acc_a[r];
        hjb[(size_t)(r0 + r) * DDIM + d] = acc_b[r];
    }

    const int lane = threadIdx.x & 63;
    const int wave = threadIdx.x >> 6;
    #pragma unroll
    for (int r = 0; r < K1_ROWS; ++r) {
        float va = acc_a[r] * wv;
        float vb = acc_b[r] * wv;
        #pragma unroll
        for (int off = 32; off >= 1; off >>= 1) {
            va += __shfl_xor(va, off, 64);
            vb += __shfl_xor(vb, off, 64);
        }
        if (lane == 0) { sRed[wave][r] = va; sRed[wave][K1_ROWS + r] = vb; }
    }
    __syncthreads();
    if (threadIdx.x < K1_ROWS) {
        int r = threadIdx.x;
        si2[r0 + r] = 0.5f * (sRed[0][r] + sRed[1][r]);
    } else if (threadIdx.x < 2 * K1_ROWS) {
        int r = threadIdx.x - K1_ROWS;
        sj2[r0 + r] = 0.5f * (sRed[0][K1_ROWS + r] + sRed[1][K1_ROWS + r]) + b2v;
    }
}

// ---------------- Kernel 2: pairwise edge logits ----------------
// out[b,i,j] = si2[b,i] + sj2[b,j] + sum_d |hi[b,i,d] + hjb[b,j,d]| * 0.5*w2[d]
__global__ __launch_bounds__(256) void edge_kernel(
    const float* __restrict__ hi, const float* __restrict__ hjb,
    const float* __restrict__ si2, const float* __restrict__ sj2,
    const float* __restrict__ W2, float* __restrict__ out)
{
    __shared__ float sHi[TILE * DDIM];
    __shared__ float sHj[TILE * DDIM];
    __shared__ float sW[DDIM];
    __shared__ float sSi[TILE];
    __shared__ float sSj[TILE];

    const int b   = blockIdx.z;
    const int i0  = blockIdx.y * TILE;
    const int j0  = blockIdx.x * TILE;
    const int tid = threadIdx.x;

    const float4* src_i = reinterpret_cast<const float4*>(hi  + ((size_t)b * SDIM + i0) * DDIM);
    const float4* src_j = reinterpret_cast<const float4*>(hjb + ((size_t)b * SDIM + j0) * DDIM);
    #pragma unroll
    for (int p = 0; p < 8; ++p) {
        int idx = p * 256 + tid;
        int row = idx >> 5, c4 = idx & 31;
        *lds_ptr4(sHi, row, c4) = src_i[idx];
        *lds_ptr4(sHj, row, c4) = src_j[idx];
    }
    if (tid < DDIM) {
        sW[tid] = 0.5f * W2[tid];
    } else if (tid < DDIM + TILE) {
        sSi[tid - DDIM] = si2[b * SDIM + i0 + (tid - DDIM)];
    } else {
        sSj[tid - DDIM - TILE] = sj2[b * SDIM + j0 + (tid - DDIM - TILE)];
    }
    __syncthreads();

    const int tx = tid & 15;   // j sub-position: cols tx + 16*c
    const int ty = tid >> 4;   // i sub-position: rows ty*4 + r
    const int ri = ty * 4;

    float acc[4][4];
    #pragma unroll
    for (int r = 0; r < 4; ++r)
        #pragma unroll
        for (int c = 0; c < 4; ++c) acc[r][c] = 0.f;

    float4 A0[4], B0[4], W0v, A1[4], B1[4], W1v;

    #define LOADCHUNK(Ax, Bx, Wx, D4) do {                                   \
        _Pragma("unroll")                                                    \
        for (int r = 0; r < 4; ++r) Ax[r] = *lds_ptr4(sHi, ri + r, (D4));    \
        _Pragma("unroll")                                                    \
        for (int c = 0; c < 4; ++c) Bx[c] = *lds_ptr4(sHj, tx + 16*c, (D4)); \
        Wx = *reinterpret_cast<const float4*>(&sW[(D4) * 4]);                \
    } while (0)

    #define COMPUTE(Ax, Bx, Wx) do {                                         \
        _Pragma("unroll")                                                    \
        for (int kk = 0; kk < 4; ++kk) {                                     \
            float wk = F4GET(Wx, kk);                                        \
            _Pragma("unroll")                                                \
            for (int r = 0; r < 4; ++r) {                                    \
                float ar = F4GET(Ax[r], kk);                                 \
                _Pragma("unroll")                                            \
                for (int c = 0; c < 4; ++c) {                                \
                    float t = ar + F4GET(Bx[c], kk);                         \
                    acc[r][c] = fmaf(fabsf(t), wk, acc[r][c]);               \
                }                                                            \
            }                                                                \
        }                                                                    \
    } while (0)

    LOADCHUNK(A0, B0, W0v, 0);
    #pragma unroll
    for (int dc4 = 0; dc4 < 32; dc4 += 2) {
        LOADCHUNK(A1, B1, W1v, dc4 + 1);
        COMPUTE(A0, B0, W0v);
        if (dc4 + 2 < 32) LOADCHUNK(A0, B0, W0v, dc4 + 2);
        COMPUTE(A1, B1, W1v);
    }
    #undef LOADCHUNK
    #undef COMPUTE

    #pragma unroll
    for (int r = 0; r < 4; ++r) {
        float sv = sSi[ri + r];
        size_t base = (size_t)b * SDIM * SDIM + (size_t)(i0 + ri + r) * SDIM + j0 + tx;
        #pragma unroll
        for (int c = 0; c < 4; ++c) {
            out[base + 16 * c] = acc[r][c] + sv + sSj[tx + 16 * c];
        }
    }
}

extern "C" void kernel_launch(void* const* d_in, const int* in_sizes, int n_in,
                              void* d_out, int out_size, void* d_ws, size_t ws_size,
                              hipStream_t stream) {
    const float* x  = (const float*)d_in[0];
    const float* W1 = (const float*)d_in[1];
    const float* b1 = (const float*)d_in[2];
    const float* W2 = (const float*)d_in[3];
    const float* b2 = (const float*)d_in[4];
    float* out = (float*)d_out;

    float* ws  = (float*)d_ws;
    float* hi  = ws;                                    // B*S*D
    float* hjb = ws + (size_t)BB * SDIM * DDIM;         // B*S*D
    float* si2 = ws + (size_t)2 * BB * SDIM * DDIM;     // B*S
    float* sj2 = si2 + (size_t)BB * SDIM;               // B*S

    proj_kernel<<<BB * SDIM / K1_ROWS, 128, 0, stream>>>(x, W1, b1, W2, b2, hi, hjb, si2, sj2);
    edge_kernel<<<dim3(SDIM / TILE, SDIM / TILE, BB), 256, 0, stream>>>(hi, hjb, si2, sj2, W2, out);
}

// Round 2
// 39.292 us; speedup vs baseline: 12.9871x; 12.9871x over previous
//
#include <hip/hip_runtime.h>

#define BB 2
#define SDIM 1024
#define DDIM 128
#define TILE 64
#define K1_ROWS 8

#define F4GET(v,k) ((k)==0?(v).x:((k)==1?(v).y:((k)==2?(v).z:(v).w)))

// Swizzled LDS float4 pointer: column-XOR on float4 granularity breaks the
// power-of-2 row stride so ds_read_b128 of distinct rows at the same d-chunk
// spreads across bank groups (A reads conflict-free, B reads 2-way = free).
__device__ __forceinline__ float4* lds_ptr4(float* base, int row, int c4) {
    int swz = c4 ^ ((row >> 1) & 7);
    return reinterpret_cast<float4*>(base + row * DDIM + swz * 4);
}

// ---------------- Kernel 1: projections + row dot products ----------------
// hi[n][d]  = sum_k x[n][k] * W1[k][d]
// hjb[n][d] = sum_k x[n][k] * W1[D+k][d] + b1[d]
// si2[n] = 0.5 * (hi[n] . w2)
// sj2[n] = 0.5 * (hjb[n] . w2) + b2
__global__ __launch_bounds__(128) void proj_kernel(
    const float* __restrict__ x, const float* __restrict__ W1,
    const float* __restrict__ b1, const float* __restrict__ W2,
    const float* __restrict__ b2,
    float* __restrict__ hi, float* __restrict__ hjb,
    float* __restrict__ si2, float* __restrict__ sj2)
{
    __shared__ float sX[K1_ROWS][DDIM];
    __shared__ float sRed[2][2 * K1_ROWS];
    const int d = threadIdx.x;
    const int r0 = blockIdx.x * K1_ROWS;

    const float4* xsrc = reinterpret_cast<const float4*>(x + (size_t)r0 * DDIM);
    float4* xdst = reinterpret_cast<float4*>(&sX[0][0]);
    #pragma unroll
    for (int p = 0; p < (K1_ROWS * DDIM / 4) / 128; ++p)
        xdst[p * 128 + d] = xsrc[p * 128 + d];
    __syncthreads();

    float acc_a[K1_ROWS], acc_b[K1_ROWS];
    #pragma unroll
    for (int r = 0; r < K1_ROWS; ++r) { acc_a[r] = 0.f; acc_b[r] = 0.f; }

    for (int k = 0; k < DDIM; k += 4) {
        float4 xv[K1_ROWS];
        #pragma unroll
        for (int r = 0; r < K1_ROWS; ++r)
            xv[r] = *reinterpret_cast<const float4*>(&sX[r][k]);
        #pragma unroll
        for (int kk = 0; kk < 4; ++kk) {
            float wa = W1[(k + kk) * DDIM + d];
            float wb = W1[(DDIM + k + kk) * DDIM + d];
            #pragma unroll
            for (int r = 0; r < K1_ROWS; ++r) {
                float xr = F4GET(xv[r], kk);
                acc_a[r] = fmaf(xr, wa, acc_a[r]);
                acc_b[r] = fmaf(xr, wb, acc_b[r]);
            }
        }
    }

    const float bv  = b1[d];
    const float wv  = W2[d];
    const float b2v = b2[0];
    #pragma unroll
    for (int r = 0; r < K1_ROWS; ++r) acc_b[r] += bv;

    #pragma unroll
    for (int r = 0; r < K1_ROWS; ++r) {
        hi [(size_t)(r0 + r) * DDIM + d] = acc_a[r];
        hjb[(size_t)(r0 + r) * DDIM + d] = acc_b[r];
    }

    const int lane = threadIdx.x & 63;
    const int wave = threadIdx.x >> 6;
    #pragma unroll
    for (int r = 0; r < K1_ROWS; ++r) {
        float va = acc_a[r] * wv;
        float vb = acc_b[r] * wv;
        #pragma unroll
        for (int off = 32; off >= 1; off >>= 1) {
            va += __shfl_xor(va, off, 64);
            vb += __shfl_xor(vb, off, 64);
        }
        if (lane == 0) { sRed[wave][r] = va; sRed[wave][K1_ROWS + r] = vb; }
    }
    __syncthreads();
    if (threadIdx.x < K1_ROWS) {
        int r = threadIdx.x;
        si2[r0 + r] = 0.5f * (sRed[0][r] + sRed[1][r]);
    } else if (threadIdx.x < 2 * K1_ROWS) {
        int r = threadIdx.x - K1_ROWS;
        sj2[r0 + r] = 0.5f * (sRed[0][K1_ROWS + r] + sRed[1][K1_ROWS + r]) + b2v;
    }
}

// ---------------- Kernel 2: pairwise edge logits ----------------
// out[b,i,j] = si2[b,i] + sj2[b,j] + sum_d |hi[b,i,d] + hjb[b,j,d]| * 0.5*w2[d]
__global__ __launch_bounds__(256) void edge_kernel(
    const float* __restrict__ hi, const float* __restrict__ hjb,
    const float* __restrict__ si2, const float* __restrict__ sj2,
    const float* __restrict__ W2, float* __restrict__ out)
{
    __shared__ float sHi[TILE * DDIM];
    __shared__ float sHj[TILE * DDIM];
    __shared__ float sW[DDIM];
    __shared__ float sSi[TILE];
    __shared__ float sSj[TILE];

    const int b   = blockIdx.z;
    const int i0  = blockIdx.y * TILE;
    const int j0  = blockIdx.x * TILE;
    const int tid = threadIdx.x;

    const float4* src_i = reinterpret_cast<const float4*>(hi  + ((size_t)b * SDIM + i0) * DDIM);
    const float4* src_j = reinterpret_cast<const float4*>(hjb + ((size_t)b * SDIM + j0) * DDIM);
    #pragma unroll
    for (int p = 0; p < 8; ++p) {
        int idx = p * 256 + tid;
        int row = idx >> 5, c4 = idx & 31;
        *lds_ptr4(sHi, row, c4) = src_i[idx];
        *lds_ptr4(sHj, row, c4) = src_j[idx];
    }
    if (tid < DDIM) {
        sW[tid] = 0.5f * W2[tid];
    } else if (tid < DDIM + TILE) {
        sSi[tid - DDIM] = si2[b * SDIM + i0 + (tid - DDIM)];
    } else {
        sSj[tid - DDIM - TILE] = sj2[b * SDIM + j0 + (tid - DDIM - TILE)];
    }
    __syncthreads();

    const int tx = tid & 15;   // j sub-position: cols tx + 16*c
    const int ty = tid >> 4;   // i sub-position: rows ty*4 + r
    const int ri = ty * 4;

    float acc[4][4];
    #pragma unroll
    for (int r = 0; r < 4; ++r)
        #pragma unroll
        for (int c = 0; c < 4; ++c) acc[r][c] = 0.f;

    // Plain chunk loop — no manual double-buffer (R1: that spilled to
    // scratch, 1.1 GB of HBM traffic). unroll 2 keeps live ranges bounded;
    // the compiler's own lgkmcnt scheduling overlaps ds_read with FMAs.
    #pragma unroll 2
    for (int dc4 = 0; dc4 < 32; ++dc4) {
        float4 A[4], Bv[4];
        #pragma unroll
        for (int r = 0; r < 4; ++r) A[r] = *lds_ptr4(sHi, ri + r, dc4);
        #pragma unroll
        for (int c = 0; c < 4; ++c) Bv[c] = *lds_ptr4(sHj, tx + 16 * c, dc4);
        float4 Wv = *reinterpret_cast<const float4*>(&sW[dc4 * 4]);

        #pragma unroll
        for (int kk = 0; kk < 4; ++kk) {
            float wk = F4GET(Wv, kk);
            #pragma unroll
            for (int r = 0; r < 4; ++r) {
                float ar = F4GET(A[r], kk);
                #pragma unroll
                for (int c = 0; c < 4; ++c) {
                    float t = ar + F4GET(Bv[c], kk);
                    acc[r][c] = fmaf(fabsf(t), wk, acc[r][c]);
                }
            }
        }
    }

    #pragma unroll
    for (int r = 0; r < 4; ++r) {
        float sv = sSi[ri + r];
        size_t base = (size_t)b * SDIM * SDIM + (size_t)(i0 + ri + r) * SDIM + j0 + tx;
        #pragma unroll
        for (int c = 0; c < 4; ++c) {
            out[base + 16 * c] = acc[r][c] + sv + sSj[tx + 16 * c];
        }
    }
}

extern "C" void kernel_launch(void* const* d_in, const int* in_sizes, int n_in,
                              void* d_out, int out_size, void* d_ws, size_t ws_size,
                              hipStream_t stream) {
    const float* x  = (const float*)d_in[0];
    const float* W1 = (const float*)d_in[1];
    const float* b1 = (const float*)d_in[2];
    const float* W2 = (const float*)d_in[3];
    const float* b2 = (const float*)d_in[4];
    float* out = (float*)d_out;

    float* ws  = (float*)d_ws;
    float* hi  = ws;                                    // B*S*D
    float* hjb = ws + (size_t)BB * SDIM * DDIM;         // B*S*D
    float* si2 = ws + (size_t)2 * BB * SDIM * DDIM;     // B*S
    float* sj2 = si2 + (size_t)BB * SDIM;               // B*S

    proj_kernel<<<BB * SDIM / K1_ROWS, 128, 0, stream>>>(x, W1, b1, W2, b2, hi, hjb, si2, sj2);
    edge_kernel<<<dim3(SDIM / TILE, SDIM / TILE, BB), 256, 0, stream>>>(hi, hjb, si2, sj2, W2, out);
}

// Round 3
// 35.716 us; speedup vs baseline: 14.2873x; 1.1001x over previous
//
#include <hip/hip_runtime.h>

#define BB 2
#define SDIM 1024
#define DDIM 128
#define TILE 64
#define K1_ROWS 4

#define F4GET(v,k) ((k)==0?(v).x:((k)==1?(v).y:((k)==2?(v).z:(v).w)))

// Swizzled LDS float4 pointer: column-XOR on float4 granularity breaks the
// power-of-2 row stride so ds_read_b128 of distinct rows at the same d-chunk
// spreads across bank groups (A reads conflict-free, B reads 2-way = free).
__device__ __forceinline__ float4* lds_ptr4(float* base, int row, int c4) {
    int swz = c4 ^ ((row >> 1) & 7);
    return reinterpret_cast<float4*>(base + row * DDIM + swz * 4);
}

// ---------------- Kernel 1: projections + row dot products ----------------
// 512 blocks x 256 threads; 4 rows/block; tid>>7 picks which W1 half this
// thread computes (half 0 -> hi, half 1 -> hjb+b1). 2 blocks/CU, 8 waves/CU.
// hi[n][d]  = sum_k x[n][k] * W1[k][d]
// hjb[n][d] = sum_k x[n][k] * W1[D+k][d] + b1[d]
// si2[n] = 0.5 * (hi[n] . w2)
// sj2[n] = 0.5 * (hjb[n] . w2) + b2
__global__ __launch_bounds__(256) void proj_kernel(
    const float* __restrict__ x, const float* __restrict__ W1,
    const float* __restrict__ b1, const float* __restrict__ W2,
    const float* __restrict__ b2,
    float* __restrict__ hi, float* __restrict__ hjb,
    float* __restrict__ si2, float* __restrict__ sj2)
{
    __shared__ float sX[K1_ROWS][DDIM];
    __shared__ float sRed[4][K1_ROWS];
    const int tid  = threadIdx.x;
    const int d    = tid & 127;
    const int half = tid >> 7;
    const int r0   = blockIdx.x * K1_ROWS;

    // Stage the 4 input rows (512 floats = 128 float4).
    if (tid < K1_ROWS * DDIM / 4) {
        reinterpret_cast<float4*>(&sX[0][0])[tid] =
            reinterpret_cast<const float4*>(x + (size_t)r0 * DDIM)[tid];
    }
    __syncthreads();

    const float* Wh = W1 + (size_t)half * DDIM * DDIM;

    float acc[K1_ROWS];
    #pragma unroll
    for (int r = 0; r < K1_ROWS; ++r) acc[r] = 0.f;

    for (int k = 0; k < DDIM; k += 4) {
        float4 xv[K1_ROWS];
        #pragma unroll
        for (int r = 0; r < K1_ROWS; ++r)
            xv[r] = *reinterpret_cast<const float4*>(&sX[r][k]);
        #pragma unroll
        for (int kk = 0; kk < 4; ++kk) {
            float w = Wh[(size_t)(k + kk) * DDIM + d];
            #pragma unroll
            for (int r = 0; r < K1_ROWS; ++r)
                acc[r] = fmaf(F4GET(xv[r], kk), w, acc[r]);
        }
    }

    if (half) {
        const float bv = b1[d];
        #pragma unroll
        for (int r = 0; r < K1_ROWS; ++r) acc[r] += bv;
    }

    float* hout = half ? hjb : hi;
    #pragma unroll
    for (int r = 0; r < K1_ROWS; ++r)
        hout[(size_t)(r0 + r) * DDIM + d] = acc[r];

    // Row dot-products with w2 (for the relu->abs rewrite constants).
    const float wv   = W2[d];
    const int   lane = tid & 63;
    const int   wave = tid >> 6;
    #pragma unroll
    for (int r = 0; r < K1_ROWS; ++r) {
        float v = acc[r] * wv;
        #pragma unroll
        for (int off = 32; off >= 1; off >>= 1)
            v += __shfl_xor(v, off, 64);
        if (lane == 0) sRed[wave][r] = v;
    }
    __syncthreads();
    if (tid < K1_ROWS) {
        si2[r0 + tid] = 0.5f * (sRed[0][tid] + sRed[1][tid]);
    } else if (tid < 2 * K1_ROWS) {
        int r = tid - K1_ROWS;
        sj2[r0 + r] = 0.5f * (sRed[2][r] + sRed[3][r]) + b2[0];
    }
}

// ---------------- Kernel 2: pairwise edge logits ----------------
// out[b,i,j] = si2[b,i] + sj2[b,j] + sum_d |hi[b,i,d] + hjb[b,j,d]| * 0.5*w2[d]
__global__ __launch_bounds__(256) void edge_kernel(
    const float* __restrict__ hi, const float* __restrict__ hjb,
    const float* __restrict__ si2, const float* __restrict__ sj2,
    const float* __restrict__ W2, float* __restrict__ out)
{
    __shared__ float sHi[TILE * DDIM];
    __shared__ float sHj[TILE * DDIM];
    __shared__ float sW[DDIM];
    __shared__ float sSi[TILE];
    __shared__ float sSj[TILE];

    const int b   = blockIdx.z;
    const int i0  = blockIdx.y * TILE;
    const int j0  = blockIdx.x * TILE;
    const int tid = threadIdx.x;

    const float4* src_i = reinterpret_cast<const float4*>(hi  + ((size_t)b * SDIM + i0) * DDIM);
    const float4* src_j = reinterpret_cast<const float4*>(hjb + ((size_t)b * SDIM + j0) * DDIM);
    #pragma unroll
    for (int p = 0; p < 8; ++p) {
        int idx = p * 256 + tid;
        int row = idx >> 5, c4 = idx & 31;
        *lds_ptr4(sHi, row, c4) = src_i[idx];
        *lds_ptr4(sHj, row, c4) = src_j[idx];
    }
    if (tid < DDIM) {
        sW[tid] = 0.5f * W2[tid];
    } else if (tid < DDIM + TILE) {
        sSi[tid - DDIM] = si2[b * SDIM + i0 + (tid - DDIM)];
    } else {
        sSj[tid - DDIM - TILE] = sj2[b * SDIM + j0 + (tid - DDIM - TILE)];
    }
    __syncthreads();

    const int tx = tid & 15;   // j sub-position: cols tx + 16*c
    const int ty = tid >> 4;   // i sub-position: rows ty*4 + r
    const int ri = ty * 4;

    float acc[4][4];
    #pragma unroll
    for (int r = 0; r < 4; ++r)
        #pragma unroll
        for (int c = 0; c < 4; ++c) acc[r][c] = 0.f;

    // Plain chunk loop — no manual double-buffer (R1: that spilled to
    // scratch, 1.1 GB of HBM traffic). unroll 2 keeps live ranges bounded;
    // the compiler's own lgkmcnt scheduling overlaps ds_read with FMAs.
    #pragma unroll 2
    for (int dc4 = 0; dc4 < 32; ++dc4) {
        float4 A[4], Bv[4];
        #pragma unroll
        for (int r = 0; r < 4; ++r) A[r] = *lds_ptr4(sHi, ri + r, dc4);
        #pragma unroll
        for (int c = 0; c < 4; ++c) Bv[c] = *lds_ptr4(sHj, tx + 16 * c, dc4);
        float4 Wv = *reinterpret_cast<const float4*>(&sW[dc4 * 4]);

        #pragma unroll
        for (int kk = 0; kk < 4; ++kk) {
            float wk = F4GET(Wv, kk);
            #pragma unroll
            for (int r = 0; r < 4; ++r) {
                float ar = F4GET(A[r], kk);
                #pragma unroll
                for (int c = 0; c < 4; ++c) {
                    float t = ar + F4GET(Bv[c], kk);
                    acc[r][c] = fmaf(fabsf(t), wk, acc[r][c]);
                }
            }
        }
    }

    #pragma unroll
    for (int r = 0; r < 4; ++r) {
        float sv = sSi[ri + r];
        size_t base = (size_t)b * SDIM * SDIM + (size_t)(i0 + ri + r) * SDIM + j0 + tx;
        #pragma unroll
        for (int c = 0; c < 4; ++c) {
            out[base + 16 * c] = acc[r][c] + sv + sSj[tx + 16 * c];
        }
    }
}

extern "C" void kernel_launch(void* const* d_in, const int* in_sizes, int n_in,
                              void* d_out, int out_size, void* d_ws, size_t ws_size,
                              hipStream_t stream) {
    const float* x  = (const float*)d_in[0];
    const float* W1 = (const float*)d_in[1];
    const float* b1 = (const float*)d_in[2];
    const float* W2 = (const float*)d_in[3];
    const float* b2 = (const float*)d_in[4];
    float* out = (float*)d_out;

    float* ws  = (float*)d_ws;
    float* hi  = ws;                                    // B*S*D
    float* hjb = ws + (size_t)BB * SDIM * DDIM;         // B*S*D
    float* si2 = ws + (size_t)2 * BB * SDIM * DDIM;     // B*S
    float* sj2 = si2 + (size_t)BB * SDIM;               // B*S

    proj_kernel<<<BB * SDIM / K1_ROWS, 256, 0, stream>>>(x, W1, b1, W2, b2, hi, hjb, si2, sj2);
    edge_kernel<<<dim3(SDIM / TILE, SDIM / TILE, BB), 256, 0, stream>>>(hi, hjb, si2, sj2, W2, out);
}